// Round 5
// baseline (564.726 us; speedup 1.0000x reference)
//
#include <hip/hip_runtime.h>

// Prop3D: x (8, 4, 512, 64) f32 -> (map_hidden, map_mask), each (8, 512, 4, 64, 65) f32.
// For rel in 0..3 (base b = 1<<rel):
//   valid (s,e): s%b==0, e<64, (e-s)%b==0, e-s>=b
//   hidden[bi,d,rel,s,e] = max(x[bi,rel,d, s .. s+k-1]), k=(e-s)>>rel
//   mask  [..same..]     = 1.0
// Everything else is 0.
//
// R5: only 16% of the output is nonzero. hipMemsetAsync zeroes the whole buffer at
// the runtime fill's demonstrated 6.2 TB/s; the kernel then writes ONLY the per-row
// valid spans (e in [s+b, 63], ~160 MB total). One wave per (bi,d,rel) plane, 4 waves
// per block, zero barriers (wave-local sparse table in LDS).

#define HIDDEN_ELEMS 68157440LL   // 8*512*4*64*65

__global__ __launch_bounds__(256) void prop3d_scatter(const float* __restrict__ x,
                                                      float* __restrict__ out) {
    const int blk  = blockIdx.x;       // 0..4095 : bi*512 + d
    const int bi   = blk >> 9;
    const int d    = blk & 511;
    const int t    = threadIdx.x;
    const int rel  = t >> 6;           // wave w handles rel = w
    const int lane = t & 63;
    const int b    = 1 << rel;
    const int bmask = b - 1;

    // Wave-local sparse table: ST[rel][s][p] = max(x[s .. s+2^p-1]) (clamped; clamped
    // entries never consumed by valid queries). Written and read by the same wave only
    // -> no __syncthreads anywhere.
    __shared__ float ST[4][64][6];

    const float* __restrict__ xr = x + (((long long)(bi * 4 + rel)) * 512 + d) * 64;
    {
        float v = xr[lane];
        ST[rel][lane][0] = v;
        #pragma unroll
        for (int p = 1; p < 6; ++p) {
            int jj = lane + (1 << (p - 1));
            jj = jj > 63 ? 63 : jj;
            float o = __shfl(v, jj, 64);   // lane jj's level-(p-1) value
            v = fmaxf(v, o);
            ST[rel][lane][p] = v;
        }
    }

    // (bi, d, rel) plane base: ((bi*512 + d)*4 + rel) * 64*65
    const long long gbase = ((long long)blk * 4 + rel) * 4160;
    float* __restrict__ outH = out + gbase;
    float* __restrict__ outM = out + HIDDEN_ELEMS + gbase;

    // Rows s = 0, b, 2b, ... with a non-empty span; span cols e = s+b .. 63.
    // Invalid cols inside the span ((e-s)%b != 0) get 0.0f — they are zero anyway
    // post-memset, but writing them keeps the store run contiguous.
    for (int s = 0; s + b < 64; s += b) {
        const int c = s + b + lane;           // column e
        if (c <= 63) {
            const int diff = c - s;
            const bool valid = (diff & bmask) == 0;
            const int k  = diff >> rel;       // window length when valid (>=1)
            const int kk = valid ? k : 1;     // clamp for safe LDS reads
            const int p  = 31 - __clz(kk);    // floor(log2(kk)), 0..5
            const float a  = ST[rel][s][p];
            const float c2 = ST[rel][s + kk - (1 << p)][p];
            const float m  = fmaxf(a, c2);
            const int o = s * 65 + c;
            outH[o] = valid ? m : 0.0f;
            outM[o] = valid ? 1.0f : 0.0f;
        }
    }
}

extern "C" void kernel_launch(void* const* d_in, const int* in_sizes, int n_in,
                              void* d_out, int out_size, void* d_ws, size_t ws_size,
                              hipStream_t stream) {
    const float* x = (const float*)d_in[0];
    float* out = (float*)d_out;
    // Zero the whole output at fill rate (graph-capturable memset node), then write
    // only the valid spans.
    hipMemsetAsync(d_out, 0, (size_t)out_size, stream);
    prop3d_scatter<<<4096, 256, 0, stream>>>(x, out);
}

// Round 6
// 527.371 us; speedup vs baseline: 1.0708x; 1.0708x over previous
//
#include <hip/hip_runtime.h>

// Prop3D: x (8, 4, 512, 64) f32 -> (map_hidden, map_mask), each (8, 512, 4, 64, 65) f32.
// For rel in 0..3 (base b = 1<<rel):
//   valid (s,e): s%b==0, e<64, (e-s)%b==0, e-s>=b
//   hidden[bi,d,rel,s,e] = max(x[bi,rel,d, s .. s+k-1]), k=(e-s)>>rel   (contiguous window!)
//   mask  [..same..]     = 1.0
// Everything else is 0. Output is hidden ++ mask, flat.
//
// FINAL (revert to R2, best measured = 527.1 µs): even blocks write the hidden map
// for one (bi,d,rel) region, odd blocks write the mask map. Each wave emits one pure,
// fully-coalesced float4 store stream.
//
// Roofline evidence (R0-R5): kernel share of dur_us ≈ 95-110 µs for 545 MB of
// mandatory dense output writes ≈ 5.5-6.0 TB/s, matching the runtime fill's
// demonstrated 6.2 TB/s write floor on this chip. Confirmed by the R5 discriminating
// experiment: replacing dense writes with memset(88 µs) + sparse scatter REGRESSED
// by +27 µs, proving the dense kernel was already at the write roofline. The
// remaining ~430 µs of dur_us is harness re-poison fill (2.18 GB @ 350 µs + smaller
// reset dispatches), outside kernel_launch's control. Four structurally distinct
// kernels (nt stores / plain stores / stream-split / hoisted-decode persistent grid)
// all landed 527-537 µs — confirming insensitivity to kernel structure at this floor.

#define HIDDEN_ELEMS 68157440LL   // 8*512*4*64*65

typedef float vfloat4 __attribute__((ext_vector_type(4)));

__global__ __launch_bounds__(256) void prop3d_kernel(const float* __restrict__ x,
                                                     float* __restrict__ out) {
    const int t   = threadIdx.x;
    const int bid = blockIdx.x;            // 0..32767
    const int gid = bid >> 1;              // 0..16383 : ((b*512)+d)*4 + rel
    const int rel = gid & 3;
    const int bmask = (1 << rel) - 1;

    if (bid & 1) {
        // ---------------- mask-only block: pure pattern stream ----------------
        vfloat4* __restrict__ outM =
            reinterpret_cast<vfloat4*>(out + HIDDEN_ELEMS) + (long long)gid * 1040;
        for (int idx = t; idx < 1040; idx += 256) {
            const int f0 = idx * 4;
            vfloat4 mv;
            #pragma unroll
            for (int u = 0; u < 4; ++u) {
                const int f = f0 + u;          // 0..4159
                const int s = f / 65;
                const int e = f - s * 65;
                const int diff = e - s;
                const bool valid = (e < 64) & (diff > 0) &
                                   ((s & bmask) == 0) & ((diff & bmask) == 0);
                mv[u] = valid ? 1.0f : 0.0f;
            }
            outM[idx] = mv;
        }
        return;
    }

    // ---------------- hidden block: sparse-table range-max ----------------
    const int d  = (gid >> 2) & 511;
    const int bi = gid >> 11;

    // ST[s][p] = max(x[s .. s+2^p-1]) (clamped; clamped entries never consumed
    // by valid queries). [s][p] layout: lanes sharing s, differing p -> spread banks.
    __shared__ float ST[64][6];

    const float* xr = x + (((long long)(bi * 4 + rel)) * 512 + d) * 64;

    if (t < 64) {
        float v = xr[t];
        ST[t][0] = v;
        #pragma unroll
        for (int p = 1; p < 6; ++p) {
            int j = t + (1 << (p - 1));
            j = j > 63 ? 63 : j;
            float o = __shfl(v, j, 64);   // lane j's level-(p-1) value
            v = fmaxf(v, o);
            ST[t][p] = v;
        }
    }
    __syncthreads();

    vfloat4* __restrict__ outH = reinterpret_cast<vfloat4*>(out) + (long long)gid * 1040;

    for (int idx = t; idx < 1040; idx += 256) {
        const int f0 = idx * 4;
        vfloat4 v;
        #pragma unroll
        for (int u = 0; u < 4; ++u) {
            const int f = f0 + u;          // 0..4159
            const int s = f / 65;
            const int e = f - s * 65;
            const int diff = e - s;
            const bool valid = (e < 64) & (diff > 0) &
                               ((s & bmask) == 0) & ((diff & bmask) == 0);
            const int k  = diff >> rel;        // window length when valid (>=1)
            const int kk = valid ? k : 1;      // clamp for safe LDS reads
            const int p  = 31 - __clz(kk);     // floor(log2(kk)), 0..5
            const float a = ST[s][p];
            const float c = ST[s + kk - (1 << p)][p];
            const float m = fmaxf(a, c);
            v[u] = valid ? m : 0.0f;
        }
        outH[idx] = v;
    }
}

extern "C" void kernel_launch(void* const* d_in, const int* in_sizes, int n_in,
                              void* d_out, int out_size, void* d_ws, size_t ws_size,
                              hipStream_t stream) {
    const float* x = (const float*)d_in[0];
    float* out = (float*)d_out;
    // 2 x (8 B * 512 D * 4 rel) blocks: even -> hidden, odd -> mask
    prop3d_kernel<<<32768, 256, 0, stream>>>(x, out);
}